// Round 3
// 388.544 us; speedup vs baseline: 1.0450x; 1.0450x over previous
//
#include <hip/hip_runtime.h>
#include <hip/hip_bf16.h>

// GIN encoder: out = BN_train( (x + scatter_sum(x[src]->dst)) @ W^T + b ), b cancels in BN.
// N=50000, F=H=512, E=160000.
// R7: retreat from counted-vmcnt dual-barrier (raced in R5/R6 per m152) to the
//     guide's VERIFIED minimum 2-phase: STAGE(next) issued BEFORE COMPUTE(cur),
//     then ONE full-drain __syncthreads() per K-tile (emits s_waitcnt vmcnt(0)
//     lgkmcnt(0) + s_barrier — compiler-guaranteed fence, no inline asm).
//     Loads for tile t+1 overlap the 32 MFMAs + ds_reads of tile t.
//     Keeps: double-buffered LDS, XOR swizzle, bijective XCD swizzle with
//     col-fastest decode (4 col-blocks sharing an A-panel adjacent on one XCD).
// ws: hb[N*512 bf16] | Wb[512*512 bf16] | s1|s2|scale|shift | flag |
//     union{ prep: deg[N] cursor[N] offs[N+1] srcbuf[E]  |  zb[N*512 bf16] }  (~103 MB)

typedef __attribute__((ext_vector_type(8))) short short8;
typedef __attribute__((ext_vector_type(4))) float floatx4;

static __device__ __forceinline__ unsigned short f2bf(float f) {
    unsigned int u = __float_as_uint(f);
    u += 0x7FFFu + ((u >> 16) & 1u);   // round-to-nearest-even
    return (unsigned short)(u >> 16);
}

static __device__ __forceinline__ void gload16(const void* g, void* l) {
    __builtin_amdgcn_global_load_lds(
        (const __attribute__((address_space(1))) unsigned int*)g,
        (__attribute__((address_space(3))) unsigned int*)l, 16, 0, 0);
}

// ---- detect whether edge_index is int64 (odd int32 words all zero) or int32 ----
__global__ void detect_dtype(const int* __restrict__ ei, int* __restrict__ flag) {
    __shared__ int any_nz;
    if (threadIdx.x == 0) any_nz = 0;
    __syncthreads();
    if (ei[2 * threadIdx.x + 1] != 0) atomicOr(&any_nz, 1);
    __syncthreads();
    if (threadIdx.x == 0) *flag = (any_nz == 0) ? 1 : 0;  // 1 => int64 layout
}

static __device__ __forceinline__ void load_edge(const int* ei, int flag, int E, int e,
                                                 int& s, int& d) {
    if (flag) {
        const long long* e64 = (const long long*)ei;
        s = (int)e64[e];
        d = (int)e64[E + e];
    } else {
        s = ei[e];
        d = ei[E + e];
    }
}

// ---- W fp32 -> bf16, zero stats + deg/cursor ----
__global__ __launch_bounds__(256) void conv_w(const float* __restrict__ W,
                                              unsigned short* __restrict__ Wb,
                                              float* __restrict__ stats /*1024 floats*/,
                                              int* __restrict__ dz, int ndz) {
    int i = blockIdx.x * 256 + threadIdx.x;   // 65536 threads x 4 elems = 512*512
    float4 v = ((const float4*)W)[i];
    ushort4 u;
    u.x = f2bf(v.x); u.y = f2bf(v.y); u.z = f2bf(v.z); u.w = f2bf(v.w);
    ((ushort4*)Wb)[i] = u;
    if (blockIdx.x == 0) {
        stats[threadIdx.x] = 0.f;
        stats[256 + threadIdx.x] = 0.f;
        stats[512 + threadIdx.x] = 0.f;
        stats[768 + threadIdx.x] = 0.f;
    }
    for (int k = i; k < ndz; k += 65536) dz[k] = 0;
}

// ---- per-dst degree count ----
__global__ __launch_bounds__(256) void deg_count(const int* __restrict__ ei,
                                                 const int* __restrict__ flag,
                                                 int* __restrict__ deg, int E, int N) {
    int e = blockIdx.x * 256 + threadIdx.x;
    if (e >= E) return;
    int s, d;
    load_edge(ei, *flag, E, e, s, d);
    if ((unsigned)d < (unsigned)N) atomicAdd(&deg[d], 1);
}

// ---- single-block exclusive scan of deg[N] -> offs[N+1] ----
__global__ __launch_bounds__(1024) void scan_deg(const int* __restrict__ deg,
                                                 int* __restrict__ offs, int N) {
    __shared__ int sums[1024];
    int t = threadIdx.x;
    int per = (N + 1023) / 1024;
    int beg = t * per, end = beg + per; if (end > N) end = N; if (beg > N) beg = N;
    int s = 0;
    for (int i = beg; i < end; ++i) s += deg[i];
    sums[t] = s;
    __syncthreads();
    for (int d = 1; d < 1024; d <<= 1) {
        int v = (t >= d) ? sums[t - d] : 0;
        __syncthreads();
        sums[t] += v;
        __syncthreads();
    }
    int run = (t > 0) ? sums[t - 1] : 0;
    for (int i = beg; i < end; ++i) { offs[i] = run; run += deg[i]; }
    if (t == 0) offs[N] = sums[1023];
}

// ---- scatter src indices into dst buckets ----
__global__ __launch_bounds__(256) void bucket_fill(const int* __restrict__ ei,
                                                   const int* __restrict__ flag,
                                                   const int* __restrict__ offs,
                                                   int* __restrict__ cursor,
                                                   int* __restrict__ srcbuf, int E, int N) {
    int e = blockIdx.x * 256 + threadIdx.x;
    if (e >= E) return;
    int s, d;
    load_edge(ei, *flag, E, e, s, d);
    if ((unsigned)d >= (unsigned)N || (unsigned)s >= (unsigned)N) return;
    int pos = offs[d] + atomicAdd(&cursor[d], 1);
    srcbuf[pos] = s;
}

// ---- h[n] = bf16( x[n] + sum_{s in bucket(n)} x[s] ); one wave per HALF row,
//      unrolled x2 so two gather loads are in flight ----
__global__ __launch_bounds__(256) void aggregate(const float* __restrict__ x,
                                                 const int* __restrict__ offs,
                                                 const int* __restrict__ srcbuf,
                                                 unsigned short* __restrict__ hb, int N) {
    int w = blockIdx.x * 4 + (threadIdx.x >> 6);
    int n = w >> 1;
    if (n >= N) return;
    int lane = (threadIdx.x & 63) + (w & 1) * 64;
    float4 a = ((const float4*)(x + (size_t)n * 512))[lane];
    float4 b = {0.f, 0.f, 0.f, 0.f};
    int beg = offs[n], end = offs[n + 1];
    int j = beg;
    for (; j + 2 <= end; j += 2) {
        int s0 = srcbuf[j], s1 = srcbuf[j + 1];
        float4 v0 = ((const float4*)(x + (size_t)s0 * 512))[lane];
        float4 v1 = ((const float4*)(x + (size_t)s1 * 512))[lane];
        a.x += v0.x; a.y += v0.y; a.z += v0.z; a.w += v0.w;
        b.x += v1.x; b.y += v1.y; b.z += v1.z; b.w += v1.w;
    }
    if (j < end) {
        int s0 = srcbuf[j];
        float4 v0 = ((const float4*)(x + (size_t)s0 * 512))[lane];
        a.x += v0.x; a.y += v0.y; a.z += v0.z; a.w += v0.w;
    }
    a.x += b.x; a.y += b.y; a.z += b.z; a.w += b.w;
    ushort4 u;
    u.x = f2bf(a.x); u.y = f2bf(a.y); u.z = f2bf(a.z); u.w = f2bf(a.w);
    ((ushort4*)(hb + (size_t)n * 512))[lane] = u;
}

// ---- z = h @ Wb^T (bf16 out), stats fused.
//      Minimum 2-phase pipeline (guide T3 recipe, no inline asm):
//        prologue: STAGE(buf0, tile0); __syncthreads();
//        loop:     STAGE(buf^1, tile t+1); COMPUTE(buf); __syncthreads(); swap
//        epilogue: COMPUTE(buf)   (no prefetch)
//      __syncthreads() emits s_waitcnt vmcnt(0) lgkmcnt(0) + s_barrier: next
//      tile is fully in LDS AND all waves are done reading the computed buffer
//      before anyone overwrites it. Loads overlap the 32 MFMAs of COMPUTE. ----
__global__ __launch_bounds__(256) void gemm_bt(const unsigned short* __restrict__ hb,
                                               const unsigned short* __restrict__ Wb,
                                               unsigned short* __restrict__ zb,
                                               float* __restrict__ s1,
                                               float* __restrict__ s2, int N, int nwg) {
    __shared__ unsigned short As[2][128 * 64];   // row-major, 64 bf16 (128 B) per row
    __shared__ unsigned short Bs[2][128 * 64];
    int tid = threadIdx.x;
    int wave = tid >> 6, lane = tid & 63;
    int quad = lane >> 4, l16 = lane & 15;
    int r8 = lane >> 3;          // 0..7: row within this wave's 8-row strip
    int c8 = lane & 7;           // 0..7: 16B chunk within 128B row
    int swz = c8 ^ r8;           // XOR swizzle (applied on global side)

    // bijective XCD swizzle (m204): chunk of ~nwg/8 consecutive work ids per XCD
    int bid = blockIdx.x;
    int q = nwg >> 3, r = nwg & 7;
    int xcd = bid & 7, idx = bid >> 3;
    int wg = (xcd < r) ? (xcd * (q + 1) + idx) : (r * (q + 1) + (xcd - r) * q + idx);
    int row0 = (wg >> 2) * 128;  // col-fastest: 4 col-blocks of one A-panel adjacent
    int col0 = (wg & 3) * 128;
    int wr = (wave >> 1) * 64, wc = (wave & 1) * 64;

    floatx4 acc[4][4] = {};

    const unsigned short* aG = hb + (size_t)row0 * 512 + swz * 8;
    const unsigned short* bG = Wb + (size_t)col0 * 512 + swz * 8;

#define STAGE(nb, k0)                                                                   \
    {                                                                                   \
        _Pragma("unroll")                                                               \
        for (int p = 0; p < 4; ++p) {                                                   \
            int strip = p * 4 + wave;            /* 0..15 */                            \
            int rt = strip * 8 + r8;             /* tile row 0..127 */                  \
            /* A rows may run past N by <48: lands in Wb region (finite) — unused */    \
            gload16(aG + (size_t)rt * 512 + (k0), As[nb] + strip * 512);                \
            gload16(bG + (size_t)rt * 512 + (k0), Bs[nb] + strip * 512);                \
        }                                                                               \
    }

#define COMPUTE(nb)                                                                     \
    {                                                                                   \
        _Pragma("unroll")                                                               \
        for (int kk = 0; kk < 2; ++kk) {                                                \
            short8 af[4], bfr[4];                                                       \
            _Pragma("unroll")                                                           \
            for (int i = 0; i < 4; ++i) {                                               \
                int ch = (kk * 4 + quad) ^ (l16 & 7);                                   \
                af[i]  = *(const short8*)(As[nb] + (wr + i * 16 + l16) * 64 + ch * 8);  \
                bfr[i] = *(const short8*)(Bs[nb] + (wc + i * 16 + l16) * 64 + ch * 8);  \
            }                                                                           \
            _Pragma("unroll")                                                           \
            for (int i = 0; i < 4; ++i)                                                 \
                _Pragma("unroll")                                                       \
                for (int j = 0; j < 4; ++j)                                             \
                    acc[i][j] = __builtin_amdgcn_mfma_f32_16x16x32_bf16(af[i], bfr[j],  \
                                                                        acc[i][j], 0, 0, 0); \
        }                                                                               \
    }

    STAGE(0, 0)
    __syncthreads();                 // tile 0 fully in LDS (vmcnt(0) drain)
    int cur = 0;
#pragma unroll
    for (int t = 0; t < 7; ++t) {
        STAGE(cur ^ 1, (t + 1) * 64) // issue next tile's 8 loads...
        COMPUTE(cur)                 // ...they overlap these 32 MFMAs + ds_reads
        __syncthreads();             // drain: tile t+1 landed; all waves done with cur
        cur ^= 1;
    }
    COMPUTE(cur)                     // tile 7, no prefetch
#undef STAGE
#undef COMPUTE

    // epilogue: C/D layout col=lane&15, row=quad*4+reg; z in bf16; stats per column
    float p1[4] = {0.f, 0.f, 0.f, 0.f}, p2[4] = {0.f, 0.f, 0.f, 0.f};
#pragma unroll
    for (int i = 0; i < 4; ++i) {
        int rl = wr + i * 16 + quad * 4;
#pragma unroll
        for (int j = 0; j < 4; ++j) {
            int col = col0 + wc + j * 16 + l16;
#pragma unroll
            for (int rr = 0; rr < 4; ++rr) {
                int grow = row0 + rl + rr;
                if (grow < N) {
                    float v = acc[i][j][rr];
                    zb[(size_t)grow * 512 + col] = f2bf(v);
                    p1[j] += v;
                    p2[j] += v * v;
                }
            }
        }
    }
#pragma unroll
    for (int j = 0; j < 4; ++j) {
        p1[j] += __shfl_xor(p1[j], 16); p1[j] += __shfl_xor(p1[j], 32);
        p2[j] += __shfl_xor(p2[j], 16); p2[j] += __shfl_xor(p2[j], 32);
    }
    float* f1 = (float*)As;       // reuse LDS: 128 + 128 floats
    float* f2 = f1 + 128;
    __syncthreads();              // all waves past final COMPUTE before LDS reuse
    if (tid < 256) f1[tid] = 0.f; // zeroes both f1 and f2
    __syncthreads();
    if (quad == 0) {
#pragma unroll
        for (int j = 0; j < 4; ++j) {
            atomicAdd(&f1[wc + j * 16 + l16], p1[j]);
            atomicAdd(&f2[wc + j * 16 + l16], p2[j]);
        }
    }
    __syncthreads();
    if (tid < 128) {
        unsafeAtomicAdd(&s1[col0 + tid], f1[tid]);
        unsafeAtomicAdd(&s2[col0 + tid], f2[tid]);
    }
}

__global__ void finalize(const float* __restrict__ s1, const float* __restrict__ s2,
                         const float* __restrict__ gamma, const float* __restrict__ beta,
                         float* __restrict__ scale, float* __restrict__ shift, int N) {
    int c = threadIdx.x;  // 512
    float inv = 1.f / (float)N;
    float mean = s1[c] * inv;
    float var = s2[c] * inv - mean * mean;
    if (var < 0.f) var = 0.f;
    float sc = gamma[c] * rsqrtf(var + 1e-5f);
    scale[c] = sc;
    shift[c] = beta[c] - mean * sc;
}

// ---- out = zb * scale[col] + shift[col]; zb bf16 -> out fp32 ----
__global__ __launch_bounds__(256) void bn_apply(const ushort4* __restrict__ zb,
                                                float4* __restrict__ out,
                                                const float4* __restrict__ scale,
                                                const float4* __restrict__ shift, int n4) {
    int i = blockIdx.x * 256 + threadIdx.x;
    if (i >= n4) return;
    int c4 = i & 127;   // 512/4 groups per row
    ushort4 u = zb[i];
    float4 sc = scale[c4], sh = shift[c4];
    float4 v;
    v.x = __uint_as_float((unsigned)u.x << 16) * sc.x + sh.x;
    v.y = __uint_as_float((unsigned)u.y << 16) * sc.y + sh.y;
    v.z = __uint_as_float((unsigned)u.z << 16) * sc.z + sh.z;
    v.w = __uint_as_float((unsigned)u.w << 16) * sc.w + sh.w;
    out[i] = v;
}

extern "C" void kernel_launch(void* const* d_in, const int* in_sizes, int n_in,
                              void* d_out, int out_size, void* d_ws, size_t ws_size,
                              hipStream_t stream) {
    const float* x     = (const float*)d_in[0];
    const int*   ei    = (const int*)d_in[1];
    const float* W     = (const float*)d_in[3];
    const float* gamma = (const float*)d_in[5];
    const float* beta  = (const float*)d_in[6];
    float* out = (float*)d_out;

    int N = in_sizes[0] / 512;   // 50000
    int E = in_sizes[1] / 2;     // 160000

    char* ws = (char*)d_ws;
    size_t off = 0;
    unsigned short* hb = (unsigned short*)(ws + off); off += (size_t)N * 512 * 2;
    unsigned short* Wb = (unsigned short*)(ws + off); off += 512 * 512 * 2;
    float* s1    = (float*)(ws + off); off += 2048;
    float* s2    = (float*)(ws + off); off += 2048;
    float* scale = (float*)(ws + off); off += 2048;
    float* shift = (float*)(ws + off); off += 2048;
    int*   flag  = (int*)(ws + off);   off += 256;
    // union region: prep buffers live until aggregate; zb written by gemm afterwards
    size_t ualias = off;
    int*   deg    = (int*)(ws + off);  off += (size_t)N * 4;
    int*   cursor = (int*)(ws + off);  off += (size_t)N * 4;
    int*   offs   = (int*)(ws + off);  off += (size_t)(N + 1) * 4 + 252; off &= ~(size_t)255;
    int*   srcbuf = (int*)(ws + off);
    unsigned short* zb = (unsigned short*)(ws + ualias);  // N*512*2 bytes, aliases prep

    int n4 = N * 128;  // float4 / ushort4 count of [N,512]
    int RB = (N + 127) / 128;    // 391 row-blocks
    int nwg = RB * 4;

    hipLaunchKernelGGL(detect_dtype, dim3(1), dim3(256), 0, stream, ei, flag);
    hipLaunchKernelGGL(conv_w, dim3(256), dim3(256), 0, stream, W, Wb, s1, deg, 2 * N);
    hipLaunchKernelGGL(deg_count, dim3((E + 255) / 256), dim3(256), 0, stream, ei, flag, deg, E, N);
    hipLaunchKernelGGL(scan_deg, dim3(1), dim3(1024), 0, stream, deg, offs, N);
    hipLaunchKernelGGL(bucket_fill, dim3((E + 255) / 256), dim3(256), 0, stream,
                       ei, flag, offs, cursor, srcbuf, E, N);
    hipLaunchKernelGGL(aggregate, dim3((2 * N + 3) / 4), dim3(256), 0, stream,
                       x, offs, srcbuf, hb, N);
    hipLaunchKernelGGL(gemm_bt, dim3(nwg), dim3(256), 0, stream,
                       hb, Wb, zb, s1, s2, N, nwg);
    hipLaunchKernelGGL(finalize, dim3(1), dim3(512), 0, stream, s1, s2, gamma, beta, scale, shift, N);
    hipLaunchKernelGGL(bn_apply, dim3((n4 + 255) / 256), dim3(256), 0, stream,
                       (const ushort4*)zb, (float4*)out, (const float4*)scale, (const float4*)shift, n4);
}